// Round 4
// baseline (247.871 us; speedup 1.0000x reference)
//
#include <hip/hip_runtime.h>
#include <stdint.h>

#define Mdim 4096
#define Kdim 4096
#define Ndim 4096

typedef __attribute__((ext_vector_type(4))) int v4i;
typedef __attribute__((ext_vector_type(16))) int v16i;

__device__ __forceinline__ void gload_lds16(const void* g, void* l) {
  __builtin_amdgcn_global_load_lds(
      (__attribute__((address_space(1))) void*)(uintptr_t)g,
      (__attribute__((address_space(3))) void*)(uint32_t)(uintptr_t)l,
      16, 0, 0);
}

// ---- pack x (int32 [M][K] -> int8 [M][K]) + row sums -----------------------
__global__ __launch_bounds__(256) void pack_x_kernel(const int* __restrict__ x,
                                                     char* __restrict__ x8,
                                                     int* __restrict__ rsx) {
  const int row = blockIdx.x;
  const int t = threadIdx.x;
  const int4* src = (const int4*)(x + (size_t)row * Kdim);
  int* dst = (int*)(x8 + (size_t)row * Kdim);
  int sum = 0;
#pragma unroll
  for (int i = 0; i < 4; ++i) {
    int4 v = src[t + 256 * i];
    sum += v.x + v.y + v.z + v.w;
    dst[t + 256 * i] =
        (v.x & 0xff) | ((v.y & 0xff) << 8) | ((v.z & 0xff) << 16) | (v.w << 24);
  }
#pragma unroll
  for (int o = 32; o > 0; o >>= 1) sum += __shfl_down(sum, o, 64);
  __shared__ int red[4];
  if ((t & 63) == 0) red[t >> 6] = sum;
  __syncthreads();
  if (t == 0) rsx[row] = red[0] + red[1] + red[2] + red[3];
}

// ---- pack + transpose y (int32 [K][N] -> int8 (y-128) [N][K]) + colsum -----
__global__ __launch_bounds__(256) void pack_yt_kernel(const int* __restrict__ y,
                                                      char* __restrict__ yt,
                                                      int* __restrict__ csy) {
  __shared__ int wt[64 * 17];
  const int t = threadIdx.x;
  const int n0 = blockIdx.x * 64;
  const int k0 = blockIdx.y * 64;
  const int c = t & 15;   // n-quad
  const int r0 = t >> 4;  // 0..15
#pragma unroll
  for (int s = 0; s < 4; ++s) {
    const int r = r0 + s * 16;
    int4 v = *(const int4*)(y + (size_t)(k0 + r) * Ndim + n0 + c * 4);
    v.x -= 128; v.y -= 128; v.z -= 128; v.w -= 128;
    wt[r * 17 + c] =
        (v.x & 0xff) | ((v.y & 0xff) << 8) | ((v.z & 0xff) << 16) | (v.w << 24);
  }
  __syncthreads();
  const int n = t >> 2;
  const int kq = t & 3;
  const int colw = n >> 2;
  const int byi = (n & 3) * 8;
  int outw[4];
  int bsum = 0;
#pragma unroll
  for (int j = 0; j < 4; ++j) {
    int b[4];
#pragma unroll
    for (int jj = 0; jj < 4; ++jj) {
      const int word = wt[(kq * 16 + j * 4 + jj) * 17 + colw];
      b[jj] = (word >> byi) & 0xff;
      bsum += (int)(char)b[jj];
    }
    outw[j] = b[0] | (b[1] << 8) | (b[2] << 16) | (b[3] << 24);
  }
  *(int4*)(yt + (size_t)(n0 + n) * Kdim + k0 + kq * 16) =
      make_int4(outw[0], outw[1], outw[2], outw[3]);
  bsum += __shfl_xor(bsum, 1, 64);
  bsum += __shfl_xor(bsum, 2, 64);
  if (kq == 0) atomicAdd(csy + n0 + n, bsum);
}

// ---- i8 GEMM: C = 7.5e-4*(A8 @ B8^T - 32*rsx[m] + 66*csy[n] - 2112*K) ------
// 256 thr / 4 waves, tile 256x128, BK=64, LDS 48KB -> TWO blocks per CU
// (8 waves/CU in two independent barrier domains: one block computes while
// the other convoys/drains). Wave owns 64x128 as 2x4 MFMAs of 32x32x32_i8.
// Staging is issued mid-compute; wave-parity ks-stagger interleaves the
// post-barrier read burst with MFMAs.
__global__ __launch_bounds__(256, 2) void gemm_i8_kernel(
    const char* __restrict__ A, const char* __restrict__ B,
    const int* __restrict__ rsx, const int* __restrict__ csy,
    float* __restrict__ out) {
  __shared__ __align__(16) char lds[2 * 24576];  // buf: [As 16K | Bs 8K]
  const int t = threadIdx.x;
  const int l = t & 63;
  const int w = t >> 6;  // 0..3, wave owns rows w*64..w*64+63, all 128 cols
  const int bm = blockIdx.y * 256;
  const int bn = blockIdx.x * 128;

  v16i acc[2][4];
#pragma unroll
  for (int i = 0; i < 2; ++i)
#pragma unroll
    for (int j = 0; j < 4; ++j)
#pragma unroll
      for (int q = 0; q < 16; ++q) acc[i][j][q] = 0;

  // Staging: thread t -> LDS row srow (+64*i), 16B slot (t&3); slot holds
  // global chunk (t&3)^((row>>1)&3); key (t>>3)&3 invariant under +64.
  const int srow = t >> 2;  // 0..63
  const int cswz = ((t & 3) ^ ((t >> 3) & 3)) * 16;
  const char* gA = A + (size_t)(bm + srow) * Kdim + cswz;
  const char* gB = B + (size_t)(bn + srow) * Kdim + cswz;

#define STAGE(buf_off, koff)                                                  \
  do {                                                                        \
    _Pragma("unroll") for (int i = 0; i < 4; ++i)                             \
        gload_lds16(gA + (koff) + (size_t)i * 64 * Kdim,                      \
                    lds + (buf_off) + i * 4096 + t * 16);                     \
    _Pragma("unroll") for (int i = 0; i < 2; ++i)                             \
        gload_lds16(gB + (koff) + (size_t)i * 64 * Kdim,                      \
                    lds + (buf_off) + 16384 + i * 4096 + t * 16);             \
  } while (0)

  const int arow = w * 64 + (l & 31);
  const int brow = l & 31;
  const int lhalf = l >> 5;
  const int lkey = (l >> 1) & 3;  // == (frag_row>>1)&3 for all frag rows

#define COMPUTE_HALF(buf_off, ks)                                             \
  do {                                                                        \
    const char* As = lds + (buf_off);                                         \
    const char* Bs = lds + (buf_off) + 16384;                                 \
    const int slot = (((ks) * 2 + lhalf) ^ lkey) * 16;                        \
    v4i a[2], b[4];                                                           \
    _Pragma("unroll") for (int i = 0; i < 2; ++i)                             \
        a[i] = *(const v4i*)(As + (arow + i * 32) * 64 + slot);               \
    _Pragma("unroll") for (int j = 0; j < 4; ++j)                             \
        b[j] = *(const v4i*)(Bs + (brow + j * 32) * 64 + slot);               \
    _Pragma("unroll") for (int i = 0; i < 2; ++i)                             \
        _Pragma("unroll") for (int j = 0; j < 4; ++j)                         \
            acc[i][j] = __builtin_amdgcn_mfma_i32_32x32x32_i8(                \
                a[i], b[j], acc[i][j], 0, 0, 0);                              \
  } while (0)

  const int ksA = w & 1;  // wave-parity stagger of the two k-halves

  STAGE(0, 0);
  __syncthreads();
  for (int kt = 0; kt < 64; kt += 2) {
    COMPUTE_HALF(0, ksA);
    STAGE(24576, (kt + 1) * 64);  // kt+1 <= 63 always
    COMPUTE_HALF(0, ksA ^ 1);
    __syncthreads();
    COMPUTE_HALF(24576, ksA);
    if (kt + 2 < 64) STAGE(0, (kt + 2) * 64);
    COMPUTE_HALF(24576, ksA ^ 1);
    __syncthreads();
  }

  // Epilogue. C/D 32x32 layout: col=lane&31, row=(r&3)+8*(r>>2)+4*(lane>>5)
  const int col = l & 31;
#pragma unroll
  for (int i = 0; i < 2; ++i) {
    const int gm0 = bm + w * 64 + i * 32;
#pragma unroll
    for (int j = 0; j < 4; ++j) {
      const int gn = bn + j * 32 + col;
      const int cs = 66 * csy[gn] - 8650752;  // -2112*4096
#pragma unroll
      for (int r = 0; r < 16; ++r) {
        const int row = (r & 3) + 8 * (r >> 2) + 4 * lhalf;
        const int gm = gm0 + row;
        const int val = acc[i][j][r] - 32 * rsx[gm] + cs;
        out[(size_t)gm * Ndim + gn] = 7.5e-4f * (float)val;
      }
    }
  }
#undef STAGE
#undef COMPUTE_HALF
}

extern "C" void kernel_launch(void* const* d_in, const int* in_sizes, int n_in,
                              void* d_out, int out_size, void* d_ws, size_t ws_size,
                              hipStream_t stream) {
  (void)in_sizes; (void)n_in; (void)out_size; (void)ws_size;
  const int* x = (const int*)d_in[0];
  const int* y = (const int*)d_in[1];
  float* out = (float*)d_out;
  char* ws = (char*)d_ws;
  char* x8 = ws;                                          // 16 MB
  char* yt = ws + (size_t)Mdim * Kdim;                    // 16 MB
  int* rsx = (int*)(ws + (size_t)Mdim * Kdim + (size_t)Kdim * Ndim);
  int* csy = rsx + Mdim;

  hipMemsetAsync(csy, 0, Ndim * sizeof(int), stream);
  pack_x_kernel<<<Mdim, 256, 0, stream>>>(x, x8, rsx);
  pack_yt_kernel<<<dim3(Ndim / 64, Kdim / 64), 256, 0, stream>>>(y, yt, csy);
  gemm_i8_kernel<<<dim3(Ndim / 128, Mdim / 256), 256, 0, stream>>>(x8, yt, rsx, csy, out);
}